// Round 7
// baseline (109.320 us; speedup 1.0000x reference)
//
#include <hip/hip_runtime.h>

// DynFilter3D: out[b,h,w,o] = sum_{i,j,t} x[b,t,h+i-1,w+j-1] * f[b,h,w,(i*9+j*3+t),o]
// x: (B=8, T=3, H=192, W=192) f32   f: (B,H,W,27,16) f32   out: (B,H,W,16) f32
// Memory-bound: f (509.6 MB) streamed exactly once (~84.5us floor at 6.3 TB/s).
//
// Round-7 structure: one block per image ROW (grid = B*H = 1536). The 3x3x194
// x-halo (7KB) is staged in LDS once, ONE barrier total, then 6 segments of
// 32 pixels stream f with no further synchronization. 8 lanes per pixel:
// lane j owns channel-quad (j&3) + tap-parity (j>>2); float4 index e = j+8m
// -> each wave instruction reads full 128B lines. Patches read directly from
// xs via compile-time per-tap offsets (cndmask on parity) - no pl table.

#define B_ 8
#define T_ 3
#define H_ 192
#define W_ 192
#define CO_ 16
#define KT_ 27            // 3*3*3 taps
#define HALO_W 194        // 192 + 2
#define XS_N (9 * HALO_W) // 1746 floats: [t*3+i][w']

// tap k = (i*3 + jw)*3 + t  ->  xs offset (relative to w) = (t*3+i)*HALO_W + jw
__host__ __device__ constexpr int tap_off(int k) {
    int t = k % 3, ij = k / 3, i = ij / 3, jw = ij % 3;
    return (t * 3 + i) * HALO_W + jw;
}

__global__ __launch_bounds__(256) void DynFilter3D_kernel(
    const float* __restrict__ x,
    const float* __restrict__ f,
    float* __restrict__ out)
{
    int blk = blockIdx.x;
    int h   = blk % H_;
    int b   = blk / H_;

    __shared__ float xs[XS_N];

    // ---- stage full-row halo once: 1746 floats, 7 rounds of 256 ----
    for (int idx = threadIdx.x; idx < XS_N; idx += 256) {
        int wp = idx % HALO_W;
        int ti = idx / HALO_W;   // t*3 + i
        int i  = ti % 3;
        int t  = ti / 3;
        int hh = h + i - 1;
        int ww = wp - 1;
        float v = 0.0f;
        if ((unsigned)hh < (unsigned)H_ && (unsigned)ww < (unsigned)W_)
            v = x[(size_t)((b * T_ + t) * H_ + hh) * W_ + ww];
        xs[idx] = v;
    }
    __syncthreads();   // the only barrier in the kernel

    int wl = threadIdx.x >> 3;   // local pixel 0..31
    int j  = threadIdx.x & 7;    // lane within pixel group
    int k0 = j >> 2;             // tap parity owned by this lane
    size_t rowbase = (size_t)(b * H_ + h) * W_;

#pragma unroll 1
    for (int seg = 0; seg < W_ / 32; ++seg) {
        int w = seg * 32 + wl;
        size_t pix = rowbase + w;
        const float4* fb = reinterpret_cast<const float4*>(f + pix * (KT_ * CO_));
        const float*  xb = xs + w;

        float4 acc = make_float4(0.f, 0.f, 0.f, 0.f);
#pragma unroll
        for (int m = 0; m < 14; ++m) {
            int e = j + 8 * m;           // float4 idx in [0,108): quad=j&3, tap=k0+2m
            if (e < KT_ * 4) {
                float4 fv = fb[e];
                constexpr int KE = 1;    // placeholder to keep m compile-time clear
                (void)KE;
                int offE = tap_off(2 * m);
                int offO = tap_off((2 * m + 1 < KT_) ? 2 * m + 1 : 2 * m);
                int off  = k0 ? offO : offE;
                float p  = xb[off];
                acc.x = fmaf(p, fv.x, acc.x);
                acc.y = fmaf(p, fv.y, acc.y);
                acc.z = fmaf(p, fv.z, acc.z);
                acc.w = fmaf(p, fv.w, acc.w);
            }
        }

        // merge the two tap-parities: lanes j and j^4 hold the same channel quad
        acc.x += __shfl_xor(acc.x, 4);
        acc.y += __shfl_xor(acc.y, 4);
        acc.z += __shfl_xor(acc.z, 4);
        acc.w += __shfl_xor(acc.w, 4);

        if (j < 4)
            reinterpret_cast<float4*>(out + pix * CO_)[j] = acc;
    }
}

extern "C" void kernel_launch(void* const* d_in, const int* in_sizes, int n_in,
                              void* d_out, int out_size, void* d_ws, size_t ws_size,
                              hipStream_t stream) {
    const float* x = (const float*)d_in[0];   // 8*3*192*192
    const float* f = (const float*)d_in[1];   // 8*192*192*27*16
    float* out = (float*)d_out;               // 8*192*192*16

    const int grid = B_ * H_;                 // 1536 row-blocks
    DynFilter3D_kernel<<<grid, 256, 0, stream>>>(x, f, out);
}

// Round 8
// 97.125 us; speedup vs baseline: 1.1256x; 1.1256x over previous
//
#include <hip/hip_runtime.h>

// DynFilter3D: out[b,h,w,o] = sum_{i,j,t} x[b,t,h+i-1,w+j-1] * f[b,h,w,(i*9+j*3+t),o]
// x: (B=8, T=3, H=192, W=192) f32   f: (B,H,W,27,16) f32   out: (B,H,W,16) f32
// Memory-bound: f (509.6 MB) streamed exactly once (~84.5us floor at 6.3 TB/s).
// BEST KNOWN (round 5, 97.3us = 5.47 TB/s effective): 8 lanes per pixel,
// lane j owns channel-quad (j&3) + tap-parity (j>>2); float4 index e = j+8m
// -> each wave instruction reads full 128B lines. Patches pre-expanded into a
// per-pixel LDS table (compile-time immediate offsets on a fixed lane base).
// Tested and rejected: nontemporal loads/stores (both granularities, -6..-13%),
// row-block prologue amortization (-12%), runtime cndmask tap offsets.

#define B_ 8
#define T_ 3
#define H_ 192
#define W_ 192
#define CO_ 16
#define KT_ 27            // 3*3*3 taps
#define PIX_PER_BLK 32    // 256 threads / 8 lanes-per-pixel
#define HALO_W 34         // 32 + 2
#define XS_N (3 * 3 * HALO_W)      // 306 floats: [t][i][w']
#define PL_N (PIX_PER_BLK * KT_)   // 864 floats: [pixel][tap]

__global__ __launch_bounds__(256) void DynFilter3D_kernel(
    const float* __restrict__ x,
    const float* __restrict__ f,
    float* __restrict__ out)
{
    // block -> (b, h, wt); 32 pixels at w0 = wt*32
    int blk = blockIdx.x;
    int wt  = blk % 6;
    int bh  = blk / 6;
    int h   = bh % H_;
    int b   = bh / H_;
    int w0  = wt * PIX_PER_BLK;

    __shared__ float xs[XS_N];
    __shared__ float pl[PL_N];

    // ---- stage x halo: 306 floats, coalesced ----
    for (int idx = threadIdx.x; idx < XS_N; idx += 256) {
        int wp = idx % HALO_W;
        int ti = idx / HALO_W;   // t*3 + i
        int i  = ti % 3;
        int t  = ti / 3;
        int hh = h + i - 1;
        int ww = w0 + wp - 1;
        float v = 0.0f;
        if ((unsigned)hh < (unsigned)H_ && (unsigned)ww < (unsigned)W_)
            v = x[(size_t)((b * T_ + t) * H_ + hh) * W_ + ww];
        xs[idx] = v;
    }
    __syncthreads();

    // ---- expand to per-pixel patch table pl[pixel][k], k = (i*3+j)*3 + t ----
    for (int idx = threadIdx.x; idx < PL_N; idx += 256) {
        int k  = idx % KT_;
        int pxl = idx / KT_;
        int t  = k % 3;
        int ij = k / 3;          // i*3 + j
        int jw = ij % 3;
        int i  = ij / 3;
        pl[idx] = xs[(t * 3 + i) * HALO_W + pxl + jw];
    }
    __syncthreads();

    int wl = threadIdx.x >> 3;   // local pixel 0..31
    int j  = threadIdx.x & 7;    // lane within pixel group
    int k0 = j >> 2;             // tap parity owned by this lane
    size_t pix = (size_t)(b * H_ + h) * W_ + w0 + wl;

    const float4* fb = reinterpret_cast<const float4*>(f + pix * (KT_ * CO_));
    const float*  pp = pl + wl * KT_ + k0;

    float4 acc = make_float4(0.f, 0.f, 0.f, 0.f);
#pragma unroll
    for (int m = 0; m < 14; ++m) {
        int e = j + 8 * m;       // float4 index in [0,108): quad = j&3, tap = k0+2m
        if (e < KT_ * 4) {
            float4 fv = fb[e];
            float  p  = pp[2 * m];
            acc.x = fmaf(p, fv.x, acc.x);
            acc.y = fmaf(p, fv.y, acc.y);
            acc.z = fmaf(p, fv.z, acc.z);
            acc.w = fmaf(p, fv.w, acc.w);
        }
    }

    // merge the two tap-parities: lanes j and j^4 hold the same channel quad
    acc.x += __shfl_xor(acc.x, 4);
    acc.y += __shfl_xor(acc.y, 4);
    acc.z += __shfl_xor(acc.z, 4);
    acc.w += __shfl_xor(acc.w, 4);

    if (j < 4)
        reinterpret_cast<float4*>(out + pix * CO_)[j] = acc;
}

extern "C" void kernel_launch(void* const* d_in, const int* in_sizes, int n_in,
                              void* d_out, int out_size, void* d_ws, size_t ws_size,
                              hipStream_t stream) {
    const float* x = (const float*)d_in[0];   // 8*3*192*192
    const float* f = (const float*)d_in[1];   // 8*192*192*27*16
    float* out = (float*)d_out;               // 8*192*192*16

    const int grid = B_ * H_ * (W_ / PIX_PER_BLK);   // 9216 blocks
    DynFilter3D_kernel<<<grid, 256, 0, stream>>>(x, f, out);
}